// Round 7
// baseline (79.859 us; speedup 1.0000x reference)
//
#include <hip/hip_runtime.h>

// Triplet margin loss: mean(relu(|a-p|^2 - |a-n|^2 + MARGIN)).
// batch: (N=4096, D=1024) fp32 (16 MB); triplets: (T=100000, 3) int32.
//
// Ladder: R1 naive 137us (L3 thrash) -> R2 XCD D-chunks 55us (L2-resident)
// -> R3 bf16 47.6us -> R4 fp8 chunked 36.5us -> R5 norm-identity+unchunked
// 34.9us (gather path ~12 TB/s: L1-miss/line-fill bound, not VALU).
// R6/R7: counting-sort triplets by ANCHOR (each row is anchor ~24x):
//   - anchor row lives in registers per bucket -> bytes 3KB -> 2KB/triplet
//   - norms diff folded into scatter (sbase)
//   - nontemporal loads for p/n rows (bypass useless L1 fill); native
//     ext_vector_type since __builtin_nontemporal_load rejects HIP uint4
//   - 2 triplets unrolled -> 4 independent 1KB loads in flight

constexpr float MARGIN = 0.2f;
constexpr int D = 1024;          // floats per row; also bytes per fp8 row
constexpr int NB = 4096;         // bucket count (= max rows supported)

typedef float f32x2 __attribute__((ext_vector_type(2)));
typedef uint  u32x4 __attribute__((ext_vector_type(4)));

// ---------------- zero counts/cursor ----------------
__global__ __launch_bounds__(256)
void zero_kernel(int* p, int n)
{
    int i = blockIdx.x * 256 + threadIdx.x;
    if (i < n) p[i] = 0;
}

// ---- Phase 0: fp32 -> fp8 (HW RNE) + fp32 row norms + anchor histogram ----
__global__ __launch_bounds__(256)
void convert_norm_hist_kernel(const float* __restrict__ in,
                              uint* __restrict__ out8,
                              float* __restrict__ norms,
                              const int* __restrict__ trip,
                              int* __restrict__ counts,
                              int nrows, int T)
{
    const int lane = threadIdx.x & 63;
    const int wib  = threadIdx.x >> 6;
    const int nw   = gridDim.x * 4;
    for (int row = blockIdx.x * 4 + wib; row < nrows; row += nw) {
        const float4* r4 = (const float4*)(in + (size_t)row * D);
        uint* o = out8 + (size_t)row * (D / 4);
        float nrm = 0.0f;
        #pragma unroll
        for (int k = 0; k < 4; ++k) {
            const float4 v = r4[lane + 64 * k];
            uint u = 0;
            u = (uint)__builtin_amdgcn_cvt_pk_fp8_f32(v.x, v.y, (int)u, false);
            u = (uint)__builtin_amdgcn_cvt_pk_fp8_f32(v.z, v.w, (int)u, true);
            o[lane + 64 * k] = u;
            nrm = fmaf(v.x, v.x, fmaf(v.y, v.y, fmaf(v.z, v.z, fmaf(v.w, v.w, nrm))));
        }
        #pragma unroll
        for (int off = 32; off > 0; off >>= 1) nrm += __shfl_xor(nrm, off, 64);
        if (lane == 0) norms[row] = nrm;
    }
    // fused anchor histogram (independent work, same launch)
    for (int t = blockIdx.x * 256 + threadIdx.x; t < T; t += gridDim.x * 256)
        atomicAdd(&counts[trip[3 * t]], 1);
}

// ---------------- exclusive scan of NB counts (1 block) ----------------
__global__ __launch_bounds__(256)
void scan_kernel(const int* __restrict__ counts, int* __restrict__ offsets)
{
    __shared__ int s[256];
    const int tid = threadIdx.x;
    const int base = tid * (NB / 256);           // 16 each
    int local[NB / 256];
    int sum = 0;
    #pragma unroll
    for (int k = 0; k < NB / 256; ++k) { local[k] = sum; sum += counts[base + k]; }
    s[tid] = sum;
    __syncthreads();
    #pragma unroll
    for (int off = 1; off < 256; off <<= 1) {
        int v = (tid >= off) ? s[tid - off] : 0;
        __syncthreads();
        s[tid] += v;
        __syncthreads();
    }
    const int prefix = (tid == 0) ? 0 : s[tid - 1];
    #pragma unroll
    for (int k = 0; k < NB / 256; ++k) offsets[base + k] = prefix + local[k];
    if (tid == 255) offsets[NB] = prefix + sum;
}

// ---------------- scatter: sorted (p,n) + folded norm base ----------------
__global__ __launch_bounds__(256)
void scatter_kernel(const int* __restrict__ trip,
                    const float* __restrict__ norms,
                    const int* __restrict__ offsets,
                    int* __restrict__ cursor,
                    int2* __restrict__ spn,
                    float* __restrict__ sbase, int T)
{
    for (int t = blockIdx.x * 256 + threadIdx.x; t < T; t += gridDim.x * 256) {
        const int ia  = trip[3 * t + 0];
        const int ip  = trip[3 * t + 1];
        const int in_ = trip[3 * t + 2];
        const int pos = offsets[ia] + atomicAdd(&cursor[ia], 1);
        spn[pos]   = make_int2(ip, in_);
        sbase[pos] = norms[ip] - norms[in_] + MARGIN;
    }
}

// ---------------- Phase 1: anchor-grouped dot kernel ----------------
__device__ __forceinline__ void unpack16(u32x4 u, float* a)
{
    #pragma unroll
    for (int j = 0; j < 4; ++j) {
        const uint w = u[j];
        const f32x2 lo = __builtin_amdgcn_cvt_pk_f32_fp8((int)w, false);
        const f32x2 hi = __builtin_amdgcn_cvt_pk_f32_fp8((int)w, true);
        a[4 * j + 0] = lo.x; a[4 * j + 1] = lo.y;
        a[4 * j + 2] = hi.x; a[4 * j + 3] = hi.y;
    }
}

__device__ __forceinline__ float dot_pn(const float* a, u32x4 pv, u32x4 nv)
{
    float dot = 0.0f;
    #pragma unroll
    for (int j = 0; j < 4; ++j) {
        const uint pu = pv[j];
        const uint nu = nv[j];
        const f32x2 p0 = __builtin_amdgcn_cvt_pk_f32_fp8((int)pu, false);
        const f32x2 p1 = __builtin_amdgcn_cvt_pk_f32_fp8((int)pu, true);
        const f32x2 n0 = __builtin_amdgcn_cvt_pk_f32_fp8((int)nu, false);
        const f32x2 n1 = __builtin_amdgcn_cvt_pk_f32_fp8((int)nu, true);
        dot = fmaf(a[4 * j + 0], n0.x - p0.x, dot);
        dot = fmaf(a[4 * j + 1], n0.y - p0.y, dot);
        dot = fmaf(a[4 * j + 2], n1.x - p1.x, dot);
        dot = fmaf(a[4 * j + 3], n1.y - p1.y, dot);
    }
    return dot;
}

#define NTLOAD(p) __builtin_nontemporal_load((const u32x4*)(p))

__global__ __launch_bounds__(256)
void dot_sorted_kernel(const unsigned char* __restrict__ batch8,
                       const int2*  __restrict__ spn,
                       const float* __restrict__ sbase,
                       const int*   __restrict__ offsets,
                       float*       __restrict__ partials, int nbuckets)
{
    const int lane = threadIdx.x & 63;
    const int wib  = threadIdx.x >> 6;
    const int wid  = blockIdx.x * 4 + wib;
    const int nw   = gridDim.x * 4;

    const unsigned char* lanebase = batch8 + lane * 16;

    float acc = 0.0f;
    for (int bh = wid; bh < 2 * nbuckets; bh += nw) {
        const int b = bh >> 1;          // bucket = anchor row
        const int h = bh & 1;           // half (stride-2 split)
        const int i0  = offsets[b] + h;
        const int end = offsets[b + 1];
        if (i0 >= end) continue;

        // anchor row -> registers (reused for the whole bucket half)
        float a[16];
        unpack16(*(const u32x4*)(lanebase + (size_t)b * D), a);

        int i = i0;
        for (; i + 2 < end; i += 4) {   // two triplets per iteration
            const int2 pn0 = spn[i];
            const int2 pn1 = spn[i + 2];
            const u32x4 pv0 = NTLOAD(lanebase + (size_t)pn0.x * D);
            const u32x4 nv0 = NTLOAD(lanebase + (size_t)pn0.y * D);
            const u32x4 pv1 = NTLOAD(lanebase + (size_t)pn1.x * D);
            const u32x4 nv1 = NTLOAD(lanebase + (size_t)pn1.y * D);

            float d0 = dot_pn(a, pv0, nv0);
            float d1 = dot_pn(a, pv1, nv1);
            #pragma unroll
            for (int off = 32; off > 0; off >>= 1) {
                d0 += __shfl_xor(d0, off, 64);
                d1 += __shfl_xor(d1, off, 64);
            }
            const float l0 = sbase[i]     + 2.0f * d0;
            const float l1 = sbase[i + 2] + 2.0f * d1;
            acc += (l0 > 0.0f ? l0 : 0.0f) + (l1 > 0.0f ? l1 : 0.0f);
        }
        if (i < end) {                  // remainder triplet
            const int2 pn0 = spn[i];
            const u32x4 pv0 = NTLOAD(lanebase + (size_t)pn0.x * D);
            const u32x4 nv0 = NTLOAD(lanebase + (size_t)pn0.y * D);
            float d0 = dot_pn(a, pv0, nv0);
            #pragma unroll
            for (int off = 32; off > 0; off >>= 1) d0 += __shfl_xor(d0, off, 64);
            const float l0 = sbase[i] + 2.0f * d0;
            acc += l0 > 0.0f ? l0 : 0.0f;
        }
    }

    __shared__ float s[4];
    if (lane == 0) s[wib] = acc;
    __syncthreads();
    if (threadIdx.x == 0)
        partials[blockIdx.x] = (s[0] + s[1]) + (s[2] + s[3]);
}

// ---------------- final scalar ----------------
__global__ __launch_bounds__(256)
void final_mean_kernel(const float* __restrict__ part, int n,
                       float* __restrict__ out, float invT)
{
    __shared__ float s[256];
    float acc = 0.0f;
    for (int i = threadIdx.x; i < n; i += 256) acc += part[i];
    s[threadIdx.x] = acc;
    __syncthreads();
    #pragma unroll
    for (int st = 128; st > 0; st >>= 1) {
        if (threadIdx.x < st) s[threadIdx.x] += s[threadIdx.x + st];
        __syncthreads();
    }
    if (threadIdx.x == 0) out[0] = s[0] * invT;
}

// ---- Fallback (fp32, one wave per triplet): correctness-safe path ----------
__global__ __launch_bounds__(256)
void triplet_full_kernel(const float* __restrict__ batch,
                         const int*   __restrict__ trip,
                         float*       __restrict__ partials, int T)
{
    const int lane = threadIdx.x & 63;
    const int wib  = threadIdx.x >> 6;
    const int wave_id = blockIdx.x * 4 + wib;
    const int n_waves = gridDim.x * 4;

    float acc = 0.0f;
    for (int t = wave_id; t < T; t += n_waves) {
        const int ia  = trip[3 * t + 0];
        const int ip  = trip[3 * t + 1];
        const int in_ = trip[3 * t + 2];
        const float4* A  = (const float4*)(batch + (size_t)ia * D);
        const float4* P  = (const float4*)(batch + (size_t)ip * D);
        const float4* Nv = (const float4*)(batch + (size_t)in_ * D);
        float dap = 0.0f, dan = 0.0f;
        #pragma unroll
        for (int c = 0; c < 4; ++c) {
            const int idx = lane + c * 64;
            float4 av = A[idx], pv = P[idx], nv = Nv[idx];
            float d;
            d = av.x - pv.x; dap += d * d;
            d = av.y - pv.y; dap += d * d;
            d = av.z - pv.z; dap += d * d;
            d = av.w - pv.w; dap += d * d;
            d = av.x - nv.x; dan += d * d;
            d = av.y - nv.y; dan += d * d;
            d = av.z - nv.z; dan += d * d;
            d = av.w - nv.w; dan += d * d;
        }
        float diff = dap - dan;
        #pragma unroll
        for (int off = 32; off > 0; off >>= 1) diff += __shfl_xor(diff, off, 64);
        const float loss = diff + MARGIN;
        acc += loss > 0.0f ? loss : 0.0f;
    }
    __shared__ float s[4];
    if (lane == 0) s[wib] = acc;
    __syncthreads();
    if (threadIdx.x == 0) partials[blockIdx.x] = (s[0] + s[1]) + (s[2] + s[3]);
}

static inline size_t align256(size_t x) { return (x + 255) & ~(size_t)255; }

extern "C" void kernel_launch(void* const* d_in, const int* in_sizes, int n_in,
                              void* d_out, int out_size, void* d_ws, size_t ws_size,
                              hipStream_t stream)
{
    const float* batch = (const float*)d_in[0];
    const int*   trip  = (const int*)d_in[1];
    float* out = (float*)d_out;
    const int T     = in_sizes[1] / 3;
    const int ND    = in_sizes[0];
    const int nrows = ND / D;

    // workspace layout
    const size_t off_fp8   = 0;
    const size_t off_norms = off_fp8   + align256((size_t)ND);
    const size_t off_cnt   = off_norms + align256((size_t)nrows * 4);
    const size_t off_cur   = off_cnt   + (size_t)NB * 4;
    const size_t off_offs  = off_cur   + (size_t)NB * 4;
    const size_t off_spn   = off_offs  + align256((size_t)(NB + 1) * 4);
    const size_t off_sbase = off_spn   + align256((size_t)T * 8);
    const size_t off_part  = off_sbase + align256((size_t)T * 4);
    const size_t need      = off_part  + 2048 * 4;

    if (nrows <= NB && ws_size >= need) {
        unsigned char* ws = (unsigned char*)d_ws;
        uint*  batch8  = (uint*)(ws + off_fp8);
        float* norms   = (float*)(ws + off_norms);
        int*   counts  = (int*)(ws + off_cnt);
        int*   cursor  = (int*)(ws + off_cur);     // contiguous with counts
        int*   offsets = (int*)(ws + off_offs);
        int2*  spn     = (int2*)(ws + off_spn);
        float* sbase   = (float*)(ws + off_sbase);
        float* part    = (float*)(ws + off_part);

        zero_kernel<<<(2 * NB + 255) / 256, 256, 0, stream>>>(counts, 2 * NB);
        convert_norm_hist_kernel<<<1024, 256, 0, stream>>>(batch, batch8, norms,
                                                           trip, counts, nrows, T);
        scan_kernel<<<1, 256, 0, stream>>>(counts, offsets);
        scatter_kernel<<<256, 256, 0, stream>>>(trip, norms, offsets, cursor,
                                                spn, sbase, T);
        dot_sorted_kernel<<<2048, 256, 0, stream>>>((unsigned char*)batch8, spn,
                                                    sbase, offsets, part, nrows);
        final_mean_kernel<<<1, 256, 0, stream>>>(part, 2048, out, 1.0f / (float)T);
    } else {
        float* part = (float*)d_ws;
        triplet_full_kernel<<<2048, 256, 0, stream>>>(batch, trip, part, T);
        final_mean_kernel<<<1, 256, 0, stream>>>(part, 2048, out, 1.0f / (float)T);
    }
}

// Round 8
// 41.634 us; speedup vs baseline: 1.9181x; 1.9181x over previous
//
#include <hip/hip_runtime.h>

// Triplet margin loss: mean(relu(|a-p|^2 - |a-n|^2 + MARGIN)).
// batch: (N=4096, D=1024) fp32 (16 MB); triplets: (T=100000, 3) int32.
//
// Ladder: R1 naive 137us (L3 thrash) -> R2 XCD D-chunks 55us (24 TB/s L2)
// -> R3 bf16 47.6 -> R4 fp8 chunked 36.5 -> R5 norm-identity unchunked 34.9
// (~12 TB/s: only 3 loads in flight/wave) -> R7 anchor-sort+NT-loads 79.9
// REGRESSION (nontemporal defeats L2 residency + bucket imbalance).
// R8: revert to R5 structure; restore MLP by processing 2 triplets per wave
// iteration (6 x 1KB loads in flight, matching R2's measured 24 TB/s point).
// Plain loads (L2-cached), VGPR kept < 64 for 8 waves/SIMD.

constexpr float MARGIN = 0.2f;
constexpr int D = 1024;          // floats per row == bytes per fp8 row

typedef float f32x2 __attribute__((ext_vector_type(2)));
typedef uint  u32x4 __attribute__((ext_vector_type(4)));

// ---- Phase 0: fp32 -> fp8 e4m3 (HW RNE) + exact fp32 row norms ----
__global__ __launch_bounds__(256)
void convert_norm_kernel(const float* __restrict__ in,
                         uint* __restrict__ out8,
                         float* __restrict__ norms, int nrows)
{
    const int lane = threadIdx.x & 63;
    const int wib  = threadIdx.x >> 6;
    const int nw   = gridDim.x * 4;
    for (int row = blockIdx.x * 4 + wib; row < nrows; row += nw) {
        const float4* r4 = (const float4*)(in + (size_t)row * D);
        uint* o = out8 + (size_t)row * (D / 4);
        float nrm = 0.0f;
        #pragma unroll
        for (int k = 0; k < 4; ++k) {
            const float4 v = r4[lane + 64 * k];
            uint u = 0;
            u = (uint)__builtin_amdgcn_cvt_pk_fp8_f32(v.x, v.y, (int)u, false);
            u = (uint)__builtin_amdgcn_cvt_pk_fp8_f32(v.z, v.w, (int)u, true);
            o[lane + 64 * k] = u;
            nrm = fmaf(v.x, v.x, fmaf(v.y, v.y, fmaf(v.z, v.z, fmaf(v.w, v.w, nrm))));
        }
        #pragma unroll
        for (int off = 32; off > 0; off >>= 1) nrm += __shfl_xor(nrm, off, 64);
        if (lane == 0) norms[row] = nrm;
    }
}

// ---- dot = a.(n-p) over this lane's 16 elements ----
__device__ __forceinline__ float dot_apn(u32x4 av, u32x4 pv, u32x4 nv)
{
    float dot = 0.0f;
    #pragma unroll
    for (int j = 0; j < 4; ++j) {
        const uint au = av[j], pu = pv[j], nu = nv[j];
        const f32x2 a0 = __builtin_amdgcn_cvt_pk_f32_fp8((int)au, false);
        const f32x2 a1 = __builtin_amdgcn_cvt_pk_f32_fp8((int)au, true);
        const f32x2 p0 = __builtin_amdgcn_cvt_pk_f32_fp8((int)pu, false);
        const f32x2 p1 = __builtin_amdgcn_cvt_pk_f32_fp8((int)pu, true);
        const f32x2 n0 = __builtin_amdgcn_cvt_pk_f32_fp8((int)nu, false);
        const f32x2 n1 = __builtin_amdgcn_cvt_pk_f32_fp8((int)nu, true);
        dot = fmaf(a0.x, n0.x - p0.x, dot);
        dot = fmaf(a0.y, n0.y - p0.y, dot);
        dot = fmaf(a1.x, n1.x - p1.x, dot);
        dot = fmaf(a1.y, n1.y - p1.y, dot);
    }
    return dot;
}

// ---- Phase 1: one wave per 2 triplets -> 6 x 1KB loads in flight ----
__global__ __launch_bounds__(256)
void triplet_dot2_kernel(const unsigned char* __restrict__ batch8,
                         const int*   __restrict__ trip,
                         const float* __restrict__ norms,
                         float*       __restrict__ partials, int T)
{
    const int lane = threadIdx.x & 63;
    const int wib  = threadIdx.x >> 6;
    const int wid  = blockIdx.x * 4 + wib;
    const int nw   = gridDim.x * 4;

    const unsigned char* base = batch8 + lane * 16;  // lane's 16B of any row

    float acc = 0.0f;
    int t = wid * 2;
    const int step = nw * 2;

    for (; t + 1 < T; t += step) {
        // 6 wave-uniform index loads (cache-broadcast)
        const int ia0 = trip[3 * t + 0];
        const int ip0 = trip[3 * t + 1];
        const int in0 = trip[3 * t + 2];
        const int ia1 = trip[3 * t + 3];
        const int ip1 = trip[3 * t + 4];
        const int in1 = trip[3 * t + 5];

        // issue all 6 row loads back-to-back (6 KB in flight per wave)
        const u32x4 av0 = *(const u32x4*)(base + (size_t)ia0 * D);
        const u32x4 pv0 = *(const u32x4*)(base + (size_t)ip0 * D);
        const u32x4 nv0 = *(const u32x4*)(base + (size_t)in0 * D);
        const u32x4 av1 = *(const u32x4*)(base + (size_t)ia1 * D);
        const u32x4 pv1 = *(const u32x4*)(base + (size_t)ip1 * D);
        const u32x4 nv1 = *(const u32x4*)(base + (size_t)in1 * D);

        float d0 = dot_apn(av0, pv0, nv0);
        float d1 = dot_apn(av1, pv1, nv1);

        // interleaved butterflies (DS pipe overlaps VALU)
        #pragma unroll
        for (int off = 32; off > 0; off >>= 1) {
            d0 += __shfl_xor(d0, off, 64);
            d1 += __shfl_xor(d1, off, 64);
        }

        const float l0 = norms[ip0] - norms[in0] + 2.0f * d0 + MARGIN;
        const float l1 = norms[ip1] - norms[in1] + 2.0f * d1 + MARGIN;
        acc += (l0 > 0.0f ? l0 : 0.0f) + (l1 > 0.0f ? l1 : 0.0f);
    }
    if (t < T) {                                   // tail (odd T)
        const int ia = trip[3 * t + 0];
        const int ip = trip[3 * t + 1];
        const int in_ = trip[3 * t + 2];
        const u32x4 av = *(const u32x4*)(base + (size_t)ia * D);
        const u32x4 pv = *(const u32x4*)(base + (size_t)ip * D);
        const u32x4 nv = *(const u32x4*)(base + (size_t)in_ * D);
        float d = dot_apn(av, pv, nv);
        #pragma unroll
        for (int off = 32; off > 0; off >>= 1) d += __shfl_xor(d, off, 64);
        const float l = norms[ip] - norms[in_] + 2.0f * d + MARGIN;
        acc += l > 0.0f ? l : 0.0f;
    }

    __shared__ float s[4];
    if (lane == 0) s[wib] = acc;
    __syncthreads();
    if (threadIdx.x == 0)
        partials[blockIdx.x] = (s[0] + s[1]) + (s[2] + s[3]);
}

// ---- final scalar ----
__global__ __launch_bounds__(256)
void final_mean_kernel(const float* __restrict__ part, int n,
                       float* __restrict__ out, float invT)
{
    __shared__ float s[256];
    float acc = 0.0f;
    for (int i = threadIdx.x; i < n; i += 256) acc += part[i];
    s[threadIdx.x] = acc;
    __syncthreads();
    #pragma unroll
    for (int st = 128; st > 0; st >>= 1) {
        if (threadIdx.x < st) s[threadIdx.x] += s[threadIdx.x + st];
        __syncthreads();
    }
    if (threadIdx.x == 0) out[0] = s[0] * invT;
}

// ---- Fallback (fp32, one wave per triplet): correctness-safe path ----
__global__ __launch_bounds__(256)
void triplet_full_kernel(const float* __restrict__ batch,
                         const int*   __restrict__ trip,
                         float*       __restrict__ partials, int T)
{
    const int lane = threadIdx.x & 63;
    const int wib  = threadIdx.x >> 6;
    const int wave_id = blockIdx.x * 4 + wib;
    const int n_waves = gridDim.x * 4;

    float acc = 0.0f;
    for (int t = wave_id; t < T; t += n_waves) {
        const int ia  = trip[3 * t + 0];
        const int ip  = trip[3 * t + 1];
        const int in_ = trip[3 * t + 2];
        const float4* A  = (const float4*)(batch + (size_t)ia * D);
        const float4* P  = (const float4*)(batch + (size_t)ip * D);
        const float4* Nv = (const float4*)(batch + (size_t)in_ * D);
        float dap = 0.0f, dan = 0.0f;
        #pragma unroll
        for (int c = 0; c < 4; ++c) {
            const int idx = lane + c * 64;
            float4 av = A[idx], pv = P[idx], nv = Nv[idx];
            float d;
            d = av.x - pv.x; dap += d * d;
            d = av.y - pv.y; dap += d * d;
            d = av.z - pv.z; dap += d * d;
            d = av.w - pv.w; dap += d * d;
            d = av.x - nv.x; dan += d * d;
            d = av.y - nv.y; dan += d * d;
            d = av.z - nv.z; dan += d * d;
            d = av.w - nv.w; dan += d * d;
        }
        float diff = dap - dan;
        #pragma unroll
        for (int off = 32; off > 0; off >>= 1) diff += __shfl_xor(diff, off, 64);
        const float loss = diff + MARGIN;
        acc += loss > 0.0f ? loss : 0.0f;
    }
    __shared__ float s[4];
    if (lane == 0) s[wib] = acc;
    __syncthreads();
    if (threadIdx.x == 0) partials[blockIdx.x] = (s[0] + s[1]) + (s[2] + s[3]);
}

static inline size_t align256(size_t x) { return (x + 255) & ~(size_t)255; }

extern "C" void kernel_launch(void* const* d_in, const int* in_sizes, int n_in,
                              void* d_out, int out_size, void* d_ws, size_t ws_size,
                              hipStream_t stream)
{
    const float* batch = (const float*)d_in[0];
    const int*   trip  = (const int*)d_in[1];
    float* out = (float*)d_out;
    const int T     = in_sizes[1] / 3;
    const int ND    = in_sizes[0];
    const int nrows = ND / D;

    const int BLOCKS = 2048;
    const size_t fp8_bytes  = align256((size_t)ND);
    const size_t norm_bytes = align256((size_t)nrows * sizeof(float));
    const size_t need = fp8_bytes + norm_bytes + (size_t)BLOCKS * sizeof(float);

    if (ws_size >= need) {
        unsigned char* batch8 = (unsigned char*)d_ws;
        float* norms    = (float*)((char*)d_ws + fp8_bytes);
        float* partials = (float*)((char*)d_ws + fp8_bytes + norm_bytes);
        convert_norm_kernel<<<1024, 256, 0, stream>>>(batch, (uint*)batch8, norms, nrows);
        triplet_dot2_kernel<<<BLOCKS, 256, 0, stream>>>(batch8, trip, norms, partials, T);
        final_mean_kernel<<<1, 256, 0, stream>>>(partials, BLOCKS, out, 1.0f / (float)T);
    } else {
        float* partials = (float*)d_ws;  // 8 KB
        triplet_full_kernel<<<BLOCKS, 256, 0, stream>>>(batch, trip, partials, T);
        final_mean_kernel<<<1, 256, 0, stream>>>(partials, BLOCKS, out, 1.0f / (float)T);
    }
}

// Round 9
// 39.112 us; speedup vs baseline: 2.0418x; 1.0645x over previous
//
#include <hip/hip_runtime.h>

// Triplet margin loss: mean(relu(|a-p|^2 - |a-n|^2 + MARGIN)).
// batch: (N=4096, D=1024) fp32 (16 MB); triplets: (T=100000, 3) int32.
//
// Ladder: R1 naive 137us -> R2 XCD D-chunks 55 (21 TB/s L2) -> R3 bf16 47.6
// -> R4 fp8 36.5 -> R5 norm-identity fp8 34.9 -> R7 anchor-sort 79.9 (REGR)
// -> R8 2-trip unroll 41.6 (REGR: MLP theory falsified).
// R9: int8 + sdot4. Same bytes as fp8 (1KB/row, 4MB total), but inner loop
// is 8x v_dot4_i32_i8 instead of 56 cvt/sub/fma: 2a.(n-p) =
// 2*(s_a*s_n*idot(a,n) - s_a*s_p*idot(a,p)), exact int accumulation,
// per-row scales, exact fp32 norms. norms+scales packed float2 (one 8B
// uniform load per row).

constexpr float MARGIN = 0.2f;
constexpr int D = 1024;          // floats per row == bytes per int8 row

typedef uint u32x4 __attribute__((ext_vector_type(4)));

#if __has_builtin(__builtin_amdgcn_sdot4)
#define SDOT4(a, b, c) __builtin_amdgcn_sdot4((int)(a), (int)(b), (c), false)
#else
__device__ __forceinline__ int SDOT4(uint a, uint b, int c)
{
    #pragma unroll
    for (int k = 0; k < 4; ++k) {
        const int av = (int)(a << (24 - 8 * k)) >> 24;
        const int bv = (int)(b << (24 - 8 * k)) >> 24;
        c += av * bv;
    }
    return c;
}
#endif

// ---- Phase 0: one wave per row: absmax -> int8 quantize + norm + scale ----
// ns[row] = (norm, scale) as float2.
__global__ __launch_bounds__(256)
void quantize_kernel(const float* __restrict__ in,
                     uint* __restrict__ out8,
                     float2* __restrict__ ns, int nrows)
{
    const int lane = threadIdx.x & 63;
    const int wib  = threadIdx.x >> 6;
    const int nw   = gridDim.x * 4;
    for (int row = blockIdx.x * 4 + wib; row < nrows; row += nw) {
        const float4* r4 = (const float4*)(in + (size_t)row * D);
        uint* o = out8 + (size_t)row * (D / 4);

        // load the whole row into registers (16 floats/lane)
        float4 v[4];
        float nrm = 0.0f, amax = 0.0f;
        #pragma unroll
        for (int k = 0; k < 4; ++k) {
            v[k] = r4[lane + 64 * k];
            nrm = fmaf(v[k].x, v[k].x, fmaf(v[k].y, v[k].y,
                  fmaf(v[k].z, v[k].z, fmaf(v[k].w, v[k].w, nrm))));
            amax = fmaxf(amax, fmaxf(fmaxf(fabsf(v[k].x), fabsf(v[k].y)),
                                     fmaxf(fabsf(v[k].z), fabsf(v[k].w))));
        }
        #pragma unroll
        for (int off = 32; off > 0; off >>= 1) {
            nrm  += __shfl_xor(nrm, off, 64);
            amax  = fmaxf(amax, __shfl_xor(amax, off, 64));
        }
        const float scale = fmaxf(amax, 1e-30f) * (1.0f / 127.0f);
        const float inv   = 127.0f / fmaxf(amax, 1e-30f);

        #pragma unroll
        for (int k = 0; k < 4; ++k) {
            int q0 = __float2int_rn(v[k].x * inv);
            int q1 = __float2int_rn(v[k].y * inv);
            int q2 = __float2int_rn(v[k].z * inv);
            int q3 = __float2int_rn(v[k].w * inv);
            const uint u = (uint)(q0 & 0xff) | ((uint)(q1 & 0xff) << 8) |
                           ((uint)(q2 & 0xff) << 16) | ((uint)(q3 & 0xff) << 24);
            o[lane + 64 * k] = u;
        }
        if (lane == 0) ns[row] = make_float2(nrm, scale);
    }
}

// ---- Phase 1: one wave per triplet; two exact int8 dots per lane ----
__global__ __launch_bounds__(256)
void triplet_idot_kernel(const unsigned char* __restrict__ batch8,
                         const int*    __restrict__ trip,
                         const float2* __restrict__ ns,
                         float*        __restrict__ partials, int T)
{
    const int lane = threadIdx.x & 63;
    const int wib  = threadIdx.x >> 6;
    const int wid  = blockIdx.x * 4 + wib;
    const int nw   = gridDim.x * 4;

    const unsigned char* base = batch8 + lane * 16;  // lane's 16B of any row

    float acc = 0.0f;
    for (int t = wid; t < T; t += nw) {
        const int ia  = trip[3 * t + 0];
        const int ip  = trip[3 * t + 1];
        const int in_ = trip[3 * t + 2];

        const u32x4 av = *(const u32x4*)(base + (size_t)ia * D);
        const u32x4 pv = *(const u32x4*)(base + (size_t)ip * D);
        const u32x4 nv = *(const u32x4*)(base + (size_t)in_ * D);

        int ian = 0, iap = 0;
        #pragma unroll
        for (int j = 0; j < 4; ++j) {
            ian = SDOT4(av[j], nv[j], ian);
            iap = SDOT4(av[j], pv[j], iap);
        }

        // wave-uniform (norm, scale) pairs: one 8B load each
        const float2 nsa = ns[ia];
        const float2 nsp = ns[ip];
        const float2 nsn = ns[in_];

        // per-lane float partial of 2*a.(n-p); int dots < 2^21, exact in f32
        float f = 2.0f * (nsa.y * nsn.y * (float)ian - nsa.y * nsp.y * (float)iap);
        #pragma unroll
        for (int off = 32; off > 0; off >>= 1) f += __shfl_xor(f, off, 64);

        const float loss = nsp.x - nsn.x + f + MARGIN;
        acc += loss > 0.0f ? loss : 0.0f;
    }

    __shared__ float s[4];
    if (lane == 0) s[wib] = acc;
    __syncthreads();
    if (threadIdx.x == 0)
        partials[blockIdx.x] = (s[0] + s[1]) + (s[2] + s[3]);
}

// ---- final scalar ----
__global__ __launch_bounds__(256)
void final_mean_kernel(const float* __restrict__ part, int n,
                       float* __restrict__ out, float invT)
{
    __shared__ float s[256];
    float acc = 0.0f;
    for (int i = threadIdx.x; i < n; i += 256) acc += part[i];
    s[threadIdx.x] = acc;
    __syncthreads();
    #pragma unroll
    for (int st = 128; st > 0; st >>= 1) {
        if (threadIdx.x < st) s[threadIdx.x] += s[threadIdx.x + st];
        __syncthreads();
    }
    if (threadIdx.x == 0) out[0] = s[0] * invT;
}

// ---- Fallback (fp32, one wave per triplet): correctness-safe path ----
__global__ __launch_bounds__(256)
void triplet_full_kernel(const float* __restrict__ batch,
                         const int*   __restrict__ trip,
                         float*       __restrict__ partials, int T)
{
    const int lane = threadIdx.x & 63;
    const int wib  = threadIdx.x >> 6;
    const int wave_id = blockIdx.x * 4 + wib;
    const int n_waves = gridDim.x * 4;

    float acc = 0.0f;
    for (int t = wave_id; t < T; t += n_waves) {
        const int ia  = trip[3 * t + 0];
        const int ip  = trip[3 * t + 1];
        const int in_ = trip[3 * t + 2];
        const float4* A  = (const float4*)(batch + (size_t)ia * D);
        const float4* P  = (const float4*)(batch + (size_t)ip * D);
        const float4* Nv = (const float4*)(batch + (size_t)in_ * D);
        float dap = 0.0f, dan = 0.0f;
        #pragma unroll
        for (int c = 0; c < 4; ++c) {
            const int idx = lane + c * 64;
            float4 av = A[idx], pv = P[idx], nv = Nv[idx];
            float d;
            d = av.x - pv.x; dap += d * d;
            d = av.y - pv.y; dap += d * d;
            d = av.z - pv.z; dap += d * d;
            d = av.w - pv.w; dap += d * d;
            d = av.x - nv.x; dan += d * d;
            d = av.y - nv.y; dan += d * d;
            d = av.z - nv.z; dan += d * d;
            d = av.w - nv.w; dan += d * d;
        }
        float diff = dap - dan;
        #pragma unroll
        for (int off = 32; off > 0; off >>= 1) diff += __shfl_xor(diff, off, 64);
        const float loss = diff + MARGIN;
        acc += loss > 0.0f ? loss : 0.0f;
    }
    __shared__ float s[4];
    if (lane == 0) s[wib] = acc;
    __syncthreads();
    if (threadIdx.x == 0) partials[blockIdx.x] = (s[0] + s[1]) + (s[2] + s[3]);
}

static inline size_t align256(size_t x) { return (x + 255) & ~(size_t)255; }

extern "C" void kernel_launch(void* const* d_in, const int* in_sizes, int n_in,
                              void* d_out, int out_size, void* d_ws, size_t ws_size,
                              hipStream_t stream)
{
    const float* batch = (const float*)d_in[0];
    const int*   trip  = (const int*)d_in[1];
    float* out = (float*)d_out;
    const int T     = in_sizes[1] / 3;
    const int ND    = in_sizes[0];
    const int nrows = ND / D;

    const int BLOCKS = 2048;
    const size_t q8_bytes = align256((size_t)ND);
    const size_t ns_bytes = align256((size_t)nrows * sizeof(float2));
    const size_t need = q8_bytes + ns_bytes + (size_t)BLOCKS * sizeof(float);

    if (ws_size >= need) {
        unsigned char* batch8 = (unsigned char*)d_ws;
        float2* ns      = (float2*)((char*)d_ws + q8_bytes);
        float*  partials = (float*)((char*)d_ws + q8_bytes + ns_bytes);
        quantize_kernel<<<1024, 256, 0, stream>>>(batch, (uint*)batch8, ns, nrows);
        triplet_idot_kernel<<<BLOCKS, 256, 0, stream>>>(batch8, trip, ns, partials, T);
        final_mean_kernel<<<1, 256, 0, stream>>>(partials, BLOCKS, out, 1.0f / (float)T);
    } else {
        float* partials = (float*)d_ws;  // 8 KB
        triplet_full_kernel<<<BLOCKS, 256, 0, stream>>>(batch, trip, partials, T);
        final_mean_kernel<<<1, 256, 0, stream>>>(partials, BLOCKS, out, 1.0f / (float)T);
    }
}